// Round 7
// baseline (867.168 us; speedup 1.0000x reference)
//
#include <hip/hip_runtime.h>
#include <hip/hip_bf16.h>
#include <math.h>
#include <string.h>

#define N_NODES 50000
#define E_EDGES 800000
#define M_PATHS 3
#define IN_F    128
#define H_HEADS 8
#define O_DIM   32
#define D_DIM   256   // H*O
#define HID_DIM 128
#define NEG_SLOPE 0.2f
#define SCAN_BLK 256
#define SCAN_NB  ((N_NODES + SCAN_BLK - 1) / SCAN_BLK)   // 196

typedef __attribute__((ext_vector_type(8))) short bf16x8;
typedef __attribute__((ext_vector_type(4))) float f32x4;

__device__ __forceinline__ float bflo(unsigned w) { return __uint_as_float(w << 16); }
__device__ __forceinline__ float bfhi(unsigned w) { return __uint_as_float(w & 0xffff0000u); }

__device__ __forceinline__ unsigned short f2bf(float f) {
    __hip_bfloat16 hb = __float2bfloat16(f);
    unsigned short us;
    memcpy(&us, &hb, 2);
    return us;
}
__device__ __forceinline__ unsigned pk_bf16(float a, float b) {
    return (unsigned)f2bf(a) | ((unsigned)f2bf(b) << 16);
}

__device__ __forceinline__ bf16x8 cvt_frag(const float* __restrict__ p) {
    union { unsigned short u[8]; bf16x8 v; } r;
    const float4 f0 = *reinterpret_cast<const float4*>(p);
    const float4 f1 = *reinterpret_cast<const float4*>(p + 4);
    r.u[0] = f2bf(f0.x); r.u[1] = f2bf(f0.y); r.u[2] = f2bf(f0.z); r.u[3] = f2bf(f0.w);
    r.u[4] = f2bf(f1.x); r.u[5] = f2bf(f1.y); r.u[6] = f2bf(f1.z); r.u[7] = f2bf(f1.w);
    return r.v;
}
__device__ __forceinline__ bf16x8 zero_frag() {
    union { unsigned short u[8]; bf16x8 v; } r = {};
    return r.v;
}

// residue (blockIdx%8) -> (metapath, range-class, nclasses)
__device__ __forceinline__ void residue_map(int res, int& m, int& c, int& r) {
    m = res < 3 ? 0 : (res < 6 ? 1 : 2);
    c = res - (m == 0 ? 0 : (m == 1 ? 3 : 6));
    r = (m == 2) ? 2 : 3;
}

// ------- batched transpose-convert: W[m] [K][C] fp32 -> Wt[m] [C][K] bf16 -------
__global__ void transpose_w(const float* __restrict__ in, unsigned short* __restrict__ out,
                            int K, int C) {
    const int m = blockIdx.y;
    int i = blockIdx.x * blockDim.x + threadIdx.x;
    if (i >= K * C) return;
    int k = i / C, c = i % C;
    out[(size_t)m * K * C + (size_t)c * K + k] = f2bf(in[(size_t)m * K * C + i]);
}

// ------- GEMM: featb(bf16) = h @ W via MFMA -------
__global__ __launch_bounds__(256) void gemm_feat_mfma(const float* __restrict__ h,
                                                      const unsigned short* __restrict__ Wt,
                                                      unsigned short* __restrict__ featb) {
    const int wave = threadIdx.x >> 6;
    const int lane = threadIdx.x & 63;
    const int l15 = lane & 15, lhi = lane >> 4;
    const int r0 = blockIdx.x * 64;
    const int c0 = wave * 64;
    f32x4 acc[4][4] = {};

    for (int ks = 0; ks < 4; ++ks) {
        bf16x8 a[4], b[4];
        #pragma unroll
        for (int rg = 0; rg < 4; rg++) {
            int row = r0 + rg * 16 + l15;
            a[rg] = (row < N_NODES) ? cvt_frag(h + (size_t)row * IN_F + ks * 32 + lhi * 8)
                                    : zero_frag();
        }
        #pragma unroll
        for (int ct = 0; ct < 4; ct++) {
            int col = c0 + ct * 16 + l15;
            b[ct] = *reinterpret_cast<const bf16x8*>(Wt + (size_t)col * IN_F + ks * 32 + lhi * 8);
        }
        #pragma unroll
        for (int rg = 0; rg < 4; rg++)
            #pragma unroll
            for (int ct = 0; ct < 4; ct++)
                acc[rg][ct] = __builtin_amdgcn_mfma_f32_16x16x32_bf16(a[rg], b[ct], acc[rg][ct], 0, 0, 0);
    }
    #pragma unroll
    for (int rg = 0; rg < 4; rg++) {
        #pragma unroll
        for (int reg = 0; reg < 4; reg++) {
            int row = r0 + rg * 16 + lhi * 4 + reg;
            if (row < N_NODES) {
                #pragma unroll
                for (int ct = 0; ct < 4; ct++) {
                    int col = c0 + ct * 16 + l15;
                    featb[(size_t)row * D_DIM + col] = f2bf(acc[rg][ct][reg]);
                }
            }
        }
    }
}

// ------- el/er -------
__global__ void attn_dots(const unsigned* __restrict__ featb,
                          const float* __restrict__ al,
                          const float* __restrict__ ar,
                          float* __restrict__ el, float* __restrict__ er) {
    int idx = blockIdx.x * blockDim.x + threadIdx.x;
    if (idx >= N_NODES * H_HEADS) return;
    int n = idx / H_HEADS, hh = idx % H_HEADS;
    const uint4* fv = (const uint4*)(featb + (size_t)n * (D_DIM / 2) + hh * (O_DIM / 2));
    const float* a = al + hh * O_DIM;
    const float* b = ar + hh * O_DIM;
    float sl = 0.f, sr = 0.f;
    #pragma unroll
    for (int q = 0; q < 4; q++) {
        uint4 v = fv[q];
        unsigned ws4[4] = {v.x, v.y, v.z, v.w};
        #pragma unroll
        for (int k = 0; k < 4; k++) {
            int o = q * 8 + k * 2;
            float f0 = bflo(ws4[k]), f1 = bfhi(ws4[k]);
            sl += f0 * a[o] + f1 * a[o + 1];
            sr += f0 * b[o] + f1 * b[o + 1];
        }
    }
    el[idx] = sl; er[idx] = sr;
}

// ------- CSR: count (dst-range partitioned, XCD-local atomics, nt streams) -------
__global__ __launch_bounds__(256) void count_all(const int* __restrict__ eidx,
                                                 int* __restrict__ deg3) {
    int m, c, r;
    residue_map(blockIdx.x & 7, m, c, r);
    const int lo = c * N_NODES / r, hi = (c + 1) * N_NODES / r;
    const int bpc = gridDim.x >> 3;
    const int w = blockIdx.x >> 3;
    const int* dst = eidx + (size_t)m * 2 * E_EDGES + E_EDGES;
    int* deg = deg3 + m * N_NODES;
    for (int e = w * 256 + threadIdx.x; e < E_EDGES; e += bpc * 256) {
        int d = __builtin_nontemporal_load(dst + e);
        if (d >= lo && d < hi) atomicAdd(&deg[d], 1);
    }
}

// ------- scan phase A: per-block partial sums -------
__global__ __launch_bounds__(256) void scan_partial(const int* __restrict__ deg3,
                                                    int* __restrict__ psum) {
    const int m = blockIdx.y, b = blockIdx.x, t = threadIdx.x;
    int i = b * SCAN_BLK + t;
    int v = (i < N_NODES) ? deg3[m * N_NODES + i] : 0;
    #pragma unroll
    for (int off = 1; off < 64; off <<= 1) v += __shfl_xor(v, off);
    __shared__ int red[4];
    if ((t & 63) == 0) red[t >> 6] = v;
    __syncthreads();
    if (t == 0) psum[m * gridDim.x + b] = red[0] + red[1] + red[2] + red[3];
}

// ------- scan phase B: exscan the partials (one block per metapath) -------
__global__ __launch_bounds__(256) void scan_offsets(int* __restrict__ psum,
                                                    int* __restrict__ rowptr3) {
    const int m = blockIdx.x, t = threadIdx.x;
    __shared__ int sh[256];
    int v = (t < SCAN_NB) ? psum[m * SCAN_NB + t] : 0;
    sh[t] = v;
    __syncthreads();
    for (int off = 1; off < 256; off <<= 1) {
        int u = (t >= off) ? sh[t - off] : 0;
        __syncthreads();
        sh[t] += u;
        __syncthreads();
    }
    if (t < SCAN_NB) psum[m * SCAN_NB + t] = sh[t] - v;   // exclusive
    if (t == 255) rowptr3[m * (N_NODES + 1) + N_NODES] = sh[255];
}

// ------- scan phase C: rowptr (+cursor copy) = block offset + local exscan -------
__global__ __launch_bounds__(256) void scan_final(const int* __restrict__ deg3,
                                                  const int* __restrict__ psum,
                                                  int* __restrict__ rowptr3,
                                                  int* __restrict__ cursor3) {
    const int m = blockIdx.y, b = blockIdx.x, t = threadIdx.x;
    int i = b * SCAN_BLK + t;
    int v = (i < N_NODES) ? deg3[m * N_NODES + i] : 0;
    __shared__ int sh[256];
    sh[t] = v;
    __syncthreads();
    for (int off = 1; off < 256; off <<= 1) {
        int u = (t >= off) ? sh[t - off] : 0;
        __syncthreads();
        sh[t] += u;
        __syncthreads();
    }
    if (i < N_NODES) {
        int rp = psum[m * SCAN_NB + b] + sh[t] - v;
        rowptr3[m * (N_NODES + 1) + i] = rp;
        cursor3[m * (N_NODES + 1) + i] = rp;
    }
}

// ------- CSR: fill (dst-range partitioned; nt streams; cursor pre-init = rowptr) -------
__global__ __launch_bounds__(256) void fill_all(const int* __restrict__ eidx,
                                                int* __restrict__ cursor3,
                                                int* __restrict__ bsrc3) {
    int m, c, r;
    residue_map(blockIdx.x & 7, m, c, r);
    const int lo = c * N_NODES / r, hi = (c + 1) * N_NODES / r;
    const int bpc = gridDim.x >> 3;
    const int w = blockIdx.x >> 3;
    const int* src = eidx + (size_t)m * 2 * E_EDGES;
    const int* dst = src + E_EDGES;
    int* cur = cursor3 + m * (N_NODES + 1);
    int* bs = bsrc3 + (size_t)m * E_EDGES;
    for (int e = w * 256 + threadIdx.x; e < E_EDGES; e += bpc * 256) {
        int d = __builtin_nontemporal_load(dst + e);
        if (d >= lo && d < hi) {
            int j = atomicAdd(&cur[d], 1);
            bs[j] = __builtin_nontemporal_load(src + e);
        }
    }
}

// ------- gather: 1 wave/node, 4 nodes/block, 2-edge unroll, bf16 z out -------
__global__ __launch_bounds__(256) void gather_z(const int* __restrict__ rowptr,
                                                const int* __restrict__ bsrc,
                                                const float* __restrict__ el,
                                                const float* __restrict__ er,
                                                const uint2* __restrict__ featb2,
                                                const float* __restrict__ bias,
                                                uint2* __restrict__ zb2) {
    const int wid = threadIdx.x >> 6;
    const int l = threadIdx.x & 63;
    const int d = blockIdx.x * 4 + wid;
    const int vh = l & 7;               // virtual head this lane evaluates exp for
    const int hh = l >> 3;              // head this lane's components belong to
    const int j0 = rowptr[d], j1 = rowptr[d + 1];
    const float erv = er[d * H_HEADS + vh];

    float den = 0.f, a0 = 0.f, a1 = 0.f, a2 = 0.f, a3 = 0.f;
    int j = j0;
    for (; j + 2 <= j1; j += 2) {
        int s0 = __builtin_nontemporal_load(bsrc + j);
        int s1 = __builtin_nontemporal_load(bsrc + j + 1);
        float y0 = el[s0 * H_HEADS + vh] + erv;
        float y1 = el[s1 * H_HEADS + vh] + erv;
        uint2 w0 = featb2[(size_t)s0 * 64 + l];
        uint2 w1 = featb2[(size_t)s1 * 64 + l];
        y0 = fmaxf(y0, NEG_SLOPE * y0);
        y1 = fmaxf(y1, NEG_SLOPE * y1);
        float q0 = __expf(y0), q1 = __expf(y1);
        float ex0 = __shfl(q0, hh), ex1 = __shfl(q1, hh);
        den += ex0 + ex1;
        a0 += ex0 * bflo(w0.x) + ex1 * bflo(w1.x);
        a1 += ex0 * bfhi(w0.x) + ex1 * bfhi(w1.x);
        a2 += ex0 * bflo(w0.y) + ex1 * bflo(w1.y);
        a3 += ex0 * bfhi(w0.y) + ex1 * bfhi(w1.y);
    }
    if (j < j1) {
        int s = __builtin_nontemporal_load(bsrc + j);
        float y = el[s * H_HEADS + vh] + erv;
        uint2 w = featb2[(size_t)s * 64 + l];
        y = fmaxf(y, NEG_SLOPE * y);
        float ex = __shfl(__expf(y), hh);
        den += ex;
        a0 += ex * bflo(w.x); a1 += ex * bfhi(w.x);
        a2 += ex * bflo(w.y); a3 += ex * bfhi(w.y);
    }
    float inv = 1.f / (den == 0.f ? 1.f : den);
    float4 b4 = ((const float4*)bias)[l];
    float x0 = a0 * inv + b4.x;
    float x1 = a1 * inv + b4.y;
    float x2 = a2 * inv + b4.z;
    float x3 = a3 * inv + b4.w;
    x0 = x0 > 0.f ? x0 : expm1f(x0);
    x1 = x1 > 0.f ? x1 : expm1f(x1);
    x2 = x2 > 0.f ? x2 : expm1f(x2);
    x3 = x3 > 0.f ? x3 : expm1f(x3);
    uint2 r;
    r.x = pk_bf16(x0, x1);
    r.y = pk_bf16(x2, x3);
    zb2[(size_t)d * 64 + l] = r;
}

// ------- semantic attention via MFMA on bf16 z -------
__global__ __launch_bounds__(256) void semantic_mfma(const unsigned short* __restrict__ zb,
                                                     const unsigned short* __restrict__ W1t,
                                                     const float* __restrict__ b1,
                                                     const float* __restrict__ W2,
                                                     float* __restrict__ wsum, int m) {
    const int wave = threadIdx.x >> 6;
    const int lane = threadIdx.x & 63;
    const int l15 = lane & 15, lhi = lane >> 4;
    const int r0 = blockIdx.x * 64 + wave * 16;
    f32x4 acc[8] = {};

    for (int ks = 0; ks < 8; ++ks) {
        int row = r0 + l15;
        bf16x8 a = (row < N_NODES)
            ? *reinterpret_cast<const bf16x8*>(zb + (size_t)row * D_DIM + ks * 32 + lhi * 8)
            : zero_frag();
        #pragma unroll
        for (int ht = 0; ht < 8; ht++) {
            int col = ht * 16 + l15;
            bf16x8 b = *reinterpret_cast<const bf16x8*>(W1t + (size_t)col * D_DIM + ks * 32 + lhi * 8);
            acc[ht] = __builtin_amdgcn_mfma_f32_16x16x32_bf16(a, b, acc[ht], 0, 0, 0);
        }
    }
    float part = 0.f;
    #pragma unroll
    for (int ht = 0; ht < 8; ht++) {
        int col = ht * 16 + l15;
        float bb = b1[col], w2 = W2[col];
        #pragma unroll
        for (int reg = 0; reg < 4; reg++) {
            int row = r0 + lhi * 4 + reg;
            if (row < N_NODES) part += tanhf(acc[ht][reg] + bb) * w2;
        }
    }
    #pragma unroll
    for (int off = 1; off < 64; off <<= 1) part += __shfl_xor(part, off);
    if (lane == 0) atomicAdd(&wsum[m], part);
}

__global__ void compute_beta(const float* __restrict__ wsum, float* __restrict__ beta) {
    float w0 = wsum[0] / N_NODES, w1 = wsum[1] / N_NODES, w2 = wsum[2] / N_NODES;
    float mx = fmaxf(w0, fmaxf(w1, w2));
    float e0 = expf(w0 - mx), e1 = expf(w1 - mx), e2 = expf(w2 - mx);
    float s = e0 + e1 + e2;
    beta[0] = e0 / s; beta[1] = e1 / s; beta[2] = e2 / s;
}

__global__ void final_mix(const unsigned* __restrict__ zb, const float* __restrict__ beta,
                          float* __restrict__ out) {
    int i = blockIdx.x * blockDim.x + threadIdx.x;
    if (i >= N_NODES * (D_DIM / 2)) return;
    const size_t stride = (size_t)N_NODES * (D_DIM / 2);
    float b0 = beta[0], b1 = beta[1], b2 = beta[2];
    unsigned w0 = zb[i], w1 = zb[stride + i], w2 = zb[2 * stride + i];
    float2 r;
    r.x = b0 * bflo(w0) + b1 * bflo(w1) + b2 * bflo(w2);
    r.y = b0 * bfhi(w0) + b1 * bfhi(w1) + b2 * bfhi(w2);
    ((float2*)out)[i] = r;
}

extern "C" void kernel_launch(void* const* d_in, const int* in_sizes, int n_in,
                              void* d_out, int out_size, void* d_ws, size_t ws_size,
                              hipStream_t stream) {
    const float* h        = (const float*)d_in[0];
    const int*   eidx     = (const int*)d_in[1];
    const float* W        = (const float*)d_in[2];
    const float* attn_l   = (const float*)d_in[3];
    const float* attn_r   = (const float*)d_in[4];
    const float* bias     = (const float*)d_in[5];
    const float* sem_W1   = (const float*)d_in[6];
    const float* sem_b1   = (const float*)d_in[7];
    const float* sem_W2   = (const float*)d_in[8];
    float* out = (float*)d_out;

    float* ws = (float*)d_ws;
    float* el   = ws;                                      // N*H
    float* er   = el + N_NODES * H_HEADS;                  // N*H
    float* wsum = er + N_NODES * H_HEADS;                  // 8
    float* beta = wsum + 8;                                // 8
    unsigned short* featb = (unsigned short*)(beta + 8);           // N*D bf16
    unsigned short* zb    = featb + (size_t)N_NODES * D_DIM;       // M*N*D bf16
    unsigned short* Wt    = zb + (size_t)M_PATHS * N_NODES * D_DIM;
    unsigned short* W1t   = Wt + (size_t)M_PATHS * D_DIM * IN_F;
    int* bsrc3   = (int*)(W1t + (size_t)HID_DIM * D_DIM);  // M*E
    int* rowptr3 = bsrc3 + (size_t)M_PATHS * E_EDGES;      // M*(N+1)
    int* cursor3 = rowptr3 + M_PATHS * (N_NODES + 1);      // M*(N+1)
    int* deg3    = cursor3 + M_PATHS * (N_NODES + 1);      // M*N
    int* psum    = deg3 + M_PATHS * N_NODES;               // M*SCAN_NB

    hipMemsetAsync(wsum, 0, 16 * sizeof(float), stream);
    hipMemsetAsync(deg3, 0, M_PATHS * N_NODES * sizeof(int), stream);

    // one-time weight prep
    transpose_w<<<dim3((IN_F * D_DIM + 255) / 256, M_PATHS), 256, 0, stream>>>(
        W, Wt, IN_F, D_DIM);
    transpose_w<<<dim3((D_DIM * HID_DIM + 255) / 256, 1), 256, 0, stream>>>(
        sem_W1, W1t, D_DIM, HID_DIM);

    // batched CSR build, dst-range partitioned per XCD residue class
    count_all<<<2048, 256, 0, stream>>>(eidx, deg3);
    scan_partial<<<dim3(SCAN_NB, M_PATHS), 256, 0, stream>>>(deg3, psum);
    scan_offsets<<<M_PATHS, 256, 0, stream>>>(psum, rowptr3);
    scan_final<<<dim3(SCAN_NB, M_PATHS), 256, 0, stream>>>(deg3, psum, rowptr3, cursor3);
    fill_all<<<2048, 256, 0, stream>>>(eidx, cursor3, bsrc3);

    for (int m = 0; m < M_PATHS; ++m) {
        const float* hm = h + (size_t)m * N_NODES * IN_F;
        unsigned short* zbm = zb + (size_t)m * N_NODES * D_DIM;

        gemm_feat_mfma<<<(N_NODES + 63) / 64, 256, 0, stream>>>(
            hm, Wt + (size_t)m * D_DIM * IN_F, featb);

        attn_dots<<<(N_NODES * H_HEADS + 255) / 256, 256, 0, stream>>>(
            (const unsigned*)featb, attn_l + m * H_HEADS * O_DIM,
            attn_r + m * H_HEADS * O_DIM, el, er);

        gather_z<<<N_NODES / 4, 256, 0, stream>>>(
            rowptr3 + m * (N_NODES + 1), bsrc3 + (size_t)m * E_EDGES, el, er,
            (const uint2*)featb, bias + m * D_DIM, (uint2*)zbm);

        semantic_mfma<<<(N_NODES + 63) / 64, 256, 0, stream>>>(
            zbm, W1t, sem_b1, sem_W2, wsum, m);
    }

    compute_beta<<<1, 1, 0, stream>>>(wsum, beta);
    final_mix<<<(N_NODES * (D_DIM / 2) + 255) / 256, 256, 0, stream>>>(
        (const unsigned*)zb, beta, out);
}

// Round 8
// 860.864 us; speedup vs baseline: 1.0073x; 1.0073x over previous
//
#include <hip/hip_runtime.h>
#include <hip/hip_bf16.h>
#include <math.h>
#include <string.h>

#define N_NODES 50000
#define E_EDGES 800000
#define M_PATHS 3
#define IN_F    128
#define H_HEADS 8
#define O_DIM   32
#define D_DIM   256   // H*O
#define HID_DIM 128
#define NEG_SLOPE 0.2f
#define SCAN_BLK 256
#define SCAN_NB  ((N_NODES + SCAN_BLK - 1) / SCAN_BLK)   // 196
#define CAP      416384        // per-class pair capacity: E/2 + 16384
#define CHUNK    2048
#define NCHUNK   ((E_EDGES + CHUNK - 1) / CHUNK)         // 391

typedef __attribute__((ext_vector_type(8))) short bf16x8;
typedef __attribute__((ext_vector_type(4))) float f32x4;

__device__ __forceinline__ float bflo(unsigned w) { return __uint_as_float(w << 16); }
__device__ __forceinline__ float bfhi(unsigned w) { return __uint_as_float(w & 0xffff0000u); }

__device__ __forceinline__ unsigned short f2bf(float f) {
    __hip_bfloat16 hb = __float2bfloat16(f);
    unsigned short us;
    memcpy(&us, &hb, 2);
    return us;
}
__device__ __forceinline__ unsigned pk_bf16(float a, float b) {
    return (unsigned)f2bf(a) | ((unsigned)f2bf(b) << 16);
}

__device__ __forceinline__ bf16x8 cvt_frag(const float* __restrict__ p) {
    union { unsigned short u[8]; bf16x8 v; } r;
    const float4 f0 = *reinterpret_cast<const float4*>(p);
    const float4 f1 = *reinterpret_cast<const float4*>(p + 4);
    r.u[0] = f2bf(f0.x); r.u[1] = f2bf(f0.y); r.u[2] = f2bf(f0.z); r.u[3] = f2bf(f0.w);
    r.u[4] = f2bf(f1.x); r.u[5] = f2bf(f1.y); r.u[6] = f2bf(f1.z); r.u[7] = f2bf(f1.w);
    return r.v;
}
__device__ __forceinline__ bf16x8 zero_frag() {
    union { unsigned short u[8]; bf16x8 v; } r = {};
    return r.v;
}

// global class id g in [0,8) -> (metapath, range-class, nclasses)
__device__ __forceinline__ void residue_map(int g, int& m, int& c, int& r) {
    m = g < 3 ? 0 : (g < 6 ? 1 : 2);
    c = g - (m == 0 ? 0 : (m == 1 ? 3 : 6));
    r = (m == 2) ? 2 : 3;
}

// ------- batched transpose-convert: W[m] [K][C] fp32 -> Wt[m] [C][K] bf16 -------
__global__ void transpose_w(const float* __restrict__ in, unsigned short* __restrict__ out,
                            int K, int C) {
    const int m = blockIdx.y;
    int i = blockIdx.x * blockDim.x + threadIdx.x;
    if (i >= K * C) return;
    int k = i / C, c = i % C;
    out[(size_t)m * K * C + (size_t)c * K + k] = f2bf(in[(size_t)m * K * C + i]);
}

// ------- GEMM: featb(bf16) = h @ W via MFMA -------
__global__ __launch_bounds__(256) void gemm_feat_mfma(const float* __restrict__ h,
                                                      const unsigned short* __restrict__ Wt,
                                                      unsigned short* __restrict__ featb) {
    const int wave = threadIdx.x >> 6;
    const int lane = threadIdx.x & 63;
    const int l15 = lane & 15, lhi = lane >> 4;
    const int r0 = blockIdx.x * 64;
    const int c0 = wave * 64;
    f32x4 acc[4][4] = {};

    for (int ks = 0; ks < 4; ++ks) {
        bf16x8 a[4], b[4];
        #pragma unroll
        for (int rg = 0; rg < 4; rg++) {
            int row = r0 + rg * 16 + l15;
            a[rg] = (row < N_NODES) ? cvt_frag(h + (size_t)row * IN_F + ks * 32 + lhi * 8)
                                    : zero_frag();
        }
        #pragma unroll
        for (int ct = 0; ct < 4; ct++) {
            int col = c0 + ct * 16 + l15;
            b[ct] = *reinterpret_cast<const bf16x8*>(Wt + (size_t)col * IN_F + ks * 32 + lhi * 8);
        }
        #pragma unroll
        for (int rg = 0; rg < 4; rg++)
            #pragma unroll
            for (int ct = 0; ct < 4; ct++)
                acc[rg][ct] = __builtin_amdgcn_mfma_f32_16x16x32_bf16(a[rg], b[ct], acc[rg][ct], 0, 0, 0);
    }
    #pragma unroll
    for (int rg = 0; rg < 4; rg++) {
        #pragma unroll
        for (int reg = 0; reg < 4; reg++) {
            int row = r0 + rg * 16 + lhi * 4 + reg;
            if (row < N_NODES) {
                #pragma unroll
                for (int ct = 0; ct < 4; ct++) {
                    int col = c0 + ct * 16 + l15;
                    featb[(size_t)row * D_DIM + col] = f2bf(acc[rg][ct][reg]);
                }
            }
        }
    }
}

// ------- el/er -------
__global__ void attn_dots(const unsigned* __restrict__ featb,
                          const float* __restrict__ al,
                          const float* __restrict__ ar,
                          float* __restrict__ el, float* __restrict__ er) {
    int idx = blockIdx.x * blockDim.x + threadIdx.x;
    if (idx >= N_NODES * H_HEADS) return;
    int n = idx / H_HEADS, hh = idx % H_HEADS;
    const uint4* fv = (const uint4*)(featb + (size_t)n * (D_DIM / 2) + hh * (O_DIM / 2));
    const float* a = al + hh * O_DIM;
    const float* b = ar + hh * O_DIM;
    float sl = 0.f, sr = 0.f;
    #pragma unroll
    for (int q = 0; q < 4; q++) {
        uint4 v = fv[q];
        unsigned ws4[4] = {v.x, v.y, v.z, v.w};
        #pragma unroll
        for (int k = 0; k < 4; k++) {
            int o = q * 8 + k * 2;
            float f0 = bflo(ws4[k]), f1 = bfhi(ws4[k]);
            sl += f0 * a[o] + f1 * a[o + 1];
            sr += f0 * b[o] + f1 * b[o + 1];
        }
    }
    el[idx] = sl; er[idx] = sr;
}

// ------- phase 1: partition edges into 8 (metapath, dst-range) pair streams -------
__global__ __launch_bounds__(256) void partition_edges(const int* __restrict__ eidx,
                                                       int* __restrict__ pcur,
                                                       long long* __restrict__ pairs) {
    const int m = blockIdx.y;
    const int g0 = (m == 0) ? 0 : (m == 1 ? 3 : 6);
    const int r = (m == 2) ? 2 : 3;
    const int b1 = N_NODES / r, b2 = 2 * N_NODES / r;
    const int e0 = blockIdx.x * CHUNK;
    const int n = min(CHUNK, E_EDGES - e0);
    const int* src = eidx + (size_t)m * 2 * E_EDGES;
    const int* dst = src + E_EDGES;

    __shared__ int lcnt[3], lbase[3], lidx[3];
    if (threadIdx.x < 3) lcnt[threadIdx.x] = 0;
    __syncthreads();

    int ds[8], ss[8], cs[8];
    #pragma unroll
    for (int k = 0; k < 8; k++) {
        int o = k * 256 + threadIdx.x;
        if (o < n) {
            int e = e0 + o;
            int d = __builtin_nontemporal_load(dst + e);
            int s = __builtin_nontemporal_load(src + e);
            int c = (d >= b1) + (d >= b2);
            ds[k] = d; ss[k] = s; cs[k] = c;
            atomicAdd(&lcnt[c], 1);
        } else cs[k] = -1;
    }
    __syncthreads();
    if (threadIdx.x < 3) {
        int cnt = lcnt[threadIdx.x];
        lbase[threadIdx.x] = (threadIdx.x < r && cnt > 0) ? atomicAdd(&pcur[g0 + threadIdx.x], cnt) : 0;
        lidx[threadIdx.x] = 0;
    }
    __syncthreads();
    #pragma unroll
    for (int k = 0; k < 8; k++) {
        if (cs[k] >= 0) {
            int c = cs[k];
            int slot = atomicAdd(&lidx[c], 1);
            long long p = ((long long)ss[k] << 32) | (unsigned)ds[k];
            pairs[(size_t)(g0 + c) * CAP + lbase[c] + slot] = p;
        }
    }
}

// ------- phase 2a: count in-degrees from compacted streams (XCD-local) -------
__global__ __launch_bounds__(256) void count_pairs(const long long* __restrict__ pairs,
                                                   const int* __restrict__ pcur,
                                                   int* __restrict__ deg3) {
    const int g = blockIdx.x & 7;
    int m, c, r;
    residue_map(g, m, c, r);
    const int n = pcur[g];
    const long long* p = pairs + (size_t)g * CAP;
    int* deg = deg3 + m * N_NODES;
    const int stride = (gridDim.x >> 3) * 256;
    for (int i = (blockIdx.x >> 3) * 256 + threadIdx.x; i < n; i += stride) {
        long long v = __builtin_nontemporal_load(p + i);
        atomicAdd(&deg[(int)(v & 0xffffffff)], 1);
    }
}

// ------- scan phase A: per-block partial sums -------
__global__ __launch_bounds__(256) void scan_partial(const int* __restrict__ deg3,
                                                    int* __restrict__ psum) {
    const int m = blockIdx.y, b = blockIdx.x, t = threadIdx.x;
    int i = b * SCAN_BLK + t;
    int v = (i < N_NODES) ? deg3[m * N_NODES + i] : 0;
    #pragma unroll
    for (int off = 1; off < 64; off <<= 1) v += __shfl_xor(v, off);
    __shared__ int red[4];
    if ((t & 63) == 0) red[t >> 6] = v;
    __syncthreads();
    if (t == 0) psum[m * gridDim.x + b] = red[0] + red[1] + red[2] + red[3];
}

// ------- scan phase B: exscan the partials (one block per metapath) -------
__global__ __launch_bounds__(256) void scan_offsets(int* __restrict__ psum,
                                                    int* __restrict__ rowptr3) {
    const int m = blockIdx.x, t = threadIdx.x;
    __shared__ int sh[256];
    int v = (t < SCAN_NB) ? psum[m * SCAN_NB + t] : 0;
    sh[t] = v;
    __syncthreads();
    for (int off = 1; off < 256; off <<= 1) {
        int u = (t >= off) ? sh[t - off] : 0;
        __syncthreads();
        sh[t] += u;
        __syncthreads();
    }
    if (t < SCAN_NB) psum[m * SCAN_NB + t] = sh[t] - v;   // exclusive
    if (t == 255) rowptr3[m * (N_NODES + 1) + N_NODES] = sh[255];
}

// ------- scan phase C: rowptr (+cursor copy) = block offset + local exscan -------
__global__ __launch_bounds__(256) void scan_final(const int* __restrict__ deg3,
                                                  const int* __restrict__ psum,
                                                  int* __restrict__ rowptr3,
                                                  int* __restrict__ cursor3) {
    const int m = blockIdx.y, b = blockIdx.x, t = threadIdx.x;
    int i = b * SCAN_BLK + t;
    int v = (i < N_NODES) ? deg3[m * N_NODES + i] : 0;
    __shared__ int sh[256];
    sh[t] = v;
    __syncthreads();
    for (int off = 1; off < 256; off <<= 1) {
        int u = (t >= off) ? sh[t - off] : 0;
        __syncthreads();
        sh[t] += u;
        __syncthreads();
    }
    if (i < N_NODES) {
        int rp = psum[m * SCAN_NB + b] + sh[t] - v;
        rowptr3[m * (N_NODES + 1) + i] = rp;
        cursor3[m * (N_NODES + 1) + i] = rp;
    }
}

// ------- phase 2b: fill bsrc from compacted streams (XCD-local window) -------
__global__ __launch_bounds__(256) void fill_pairs(const long long* __restrict__ pairs,
                                                  const int* __restrict__ pcur,
                                                  int* __restrict__ cursor3,
                                                  int* __restrict__ bsrc3) {
    const int g = blockIdx.x & 7;
    int m, c, r;
    residue_map(g, m, c, r);
    const int n = pcur[g];
    const long long* p = pairs + (size_t)g * CAP;
    int* cur = cursor3 + m * (N_NODES + 1);
    int* bs = bsrc3 + (size_t)m * E_EDGES;
    const int stride = (gridDim.x >> 3) * 256;
    for (int i = (blockIdx.x >> 3) * 256 + threadIdx.x; i < n; i += stride) {
        long long v = __builtin_nontemporal_load(p + i);
        int d = (int)(v & 0xffffffff);
        int j = atomicAdd(&cur[d], 1);
        bs[j] = (int)(v >> 32);
    }
}

// ------- gather: 1 wave/node, 4 nodes/block, 2-edge unroll, bf16 z out -------
__global__ __launch_bounds__(256) void gather_z(const int* __restrict__ rowptr,
                                                const int* __restrict__ bsrc,
                                                const float* __restrict__ el,
                                                const float* __restrict__ er,
                                                const uint2* __restrict__ featb2,
                                                const float* __restrict__ bias,
                                                uint2* __restrict__ zb2) {
    const int wid = threadIdx.x >> 6;
    const int l = threadIdx.x & 63;
    const int d = blockIdx.x * 4 + wid;
    const int vh = l & 7;               // virtual head this lane evaluates exp for
    const int hh = l >> 3;              // head this lane's components belong to
    const int j0 = rowptr[d], j1 = rowptr[d + 1];
    const float erv = er[d * H_HEADS + vh];

    float den = 0.f, a0 = 0.f, a1 = 0.f, a2 = 0.f, a3 = 0.f;
    int j = j0;
    for (; j + 2 <= j1; j += 2) {
        int s0 = bsrc[j], s1 = bsrc[j + 1];
        float y0 = el[s0 * H_HEADS + vh] + erv;
        float y1 = el[s1 * H_HEADS + vh] + erv;
        uint2 w0 = featb2[(size_t)s0 * 64 + l];
        uint2 w1 = featb2[(size_t)s1 * 64 + l];
        y0 = fmaxf(y0, NEG_SLOPE * y0);
        y1 = fmaxf(y1, NEG_SLOPE * y1);
        float q0 = __expf(y0), q1 = __expf(y1);
        float ex0 = __shfl(q0, hh), ex1 = __shfl(q1, hh);
        den += ex0 + ex1;
        a0 += ex0 * bflo(w0.x) + ex1 * bflo(w1.x);
        a1 += ex0 * bfhi(w0.x) + ex1 * bfhi(w1.x);
        a2 += ex0 * bflo(w0.y) + ex1 * bflo(w1.y);
        a3 += ex0 * bfhi(w0.y) + ex1 * bfhi(w1.y);
    }
    if (j < j1) {
        int s = bsrc[j];
        float y = el[s * H_HEADS + vh] + erv;
        uint2 w = featb2[(size_t)s * 64 + l];
        y = fmaxf(y, NEG_SLOPE * y);
        float ex = __shfl(__expf(y), hh);
        den += ex;
        a0 += ex * bflo(w.x); a1 += ex * bfhi(w.x);
        a2 += ex * bflo(w.y); a3 += ex * bfhi(w.y);
    }
    float inv = 1.f / (den == 0.f ? 1.f : den);
    float4 b4 = ((const float4*)bias)[l];
    float x0 = a0 * inv + b4.x;
    float x1 = a1 * inv + b4.y;
    float x2 = a2 * inv + b4.z;
    float x3 = a3 * inv + b4.w;
    x0 = x0 > 0.f ? x0 : expm1f(x0);
    x1 = x1 > 0.f ? x1 : expm1f(x1);
    x2 = x2 > 0.f ? x2 : expm1f(x2);
    x3 = x3 > 0.f ? x3 : expm1f(x3);
    uint2 r;
    r.x = pk_bf16(x0, x1);
    r.y = pk_bf16(x2, x3);
    zb2[(size_t)d * 64 + l] = r;
}

// ------- semantic attention via MFMA on bf16 z -------
__global__ __launch_bounds__(256) void semantic_mfma(const unsigned short* __restrict__ zb,
                                                     const unsigned short* __restrict__ W1t,
                                                     const float* __restrict__ b1,
                                                     const float* __restrict__ W2,
                                                     float* __restrict__ wsum, int m) {
    const int wave = threadIdx.x >> 6;
    const int lane = threadIdx.x & 63;
    const int l15 = lane & 15, lhi = lane >> 4;
    const int r0 = blockIdx.x * 64 + wave * 16;
    f32x4 acc[8] = {};

    for (int ks = 0; ks < 8; ++ks) {
        int row = r0 + l15;
        bf16x8 a = (row < N_NODES)
            ? *reinterpret_cast<const bf16x8*>(zb + (size_t)row * D_DIM + ks * 32 + lhi * 8)
            : zero_frag();
        #pragma unroll
        for (int ht = 0; ht < 8; ht++) {
            int col = ht * 16 + l15;
            bf16x8 b = *reinterpret_cast<const bf16x8*>(W1t + (size_t)col * D_DIM + ks * 32 + lhi * 8);
            acc[ht] = __builtin_amdgcn_mfma_f32_16x16x32_bf16(a, b, acc[ht], 0, 0, 0);
        }
    }
    float part = 0.f;
    #pragma unroll
    for (int ht = 0; ht < 8; ht++) {
        int col = ht * 16 + l15;
        float bb = b1[col], w2 = W2[col];
        #pragma unroll
        for (int reg = 0; reg < 4; reg++) {
            int row = r0 + lhi * 4 + reg;
            if (row < N_NODES) part += tanhf(acc[ht][reg] + bb) * w2;
        }
    }
    #pragma unroll
    for (int off = 1; off < 64; off <<= 1) part += __shfl_xor(part, off);
    if (lane == 0) atomicAdd(&wsum[m], part);
}

__global__ void compute_beta(const float* __restrict__ wsum, float* __restrict__ beta) {
    float w0 = wsum[0] / N_NODES, w1 = wsum[1] / N_NODES, w2 = wsum[2] / N_NODES;
    float mx = fmaxf(w0, fmaxf(w1, w2));
    float e0 = expf(w0 - mx), e1 = expf(w1 - mx), e2 = expf(w2 - mx);
    float s = e0 + e1 + e2;
    beta[0] = e0 / s; beta[1] = e1 / s; beta[2] = e2 / s;
}

__global__ void final_mix(const unsigned* __restrict__ zb, const float* __restrict__ beta,
                          float* __restrict__ out) {
    int i = blockIdx.x * blockDim.x + threadIdx.x;
    if (i >= N_NODES * (D_DIM / 2)) return;
    const size_t stride = (size_t)N_NODES * (D_DIM / 2);
    float b0 = beta[0], b1 = beta[1], b2 = beta[2];
    unsigned w0 = zb[i], w1 = zb[stride + i], w2 = zb[2 * stride + i];
    float2 r;
    r.x = b0 * bflo(w0) + b1 * bflo(w1) + b2 * bflo(w2);
    r.y = b0 * bfhi(w0) + b1 * bfhi(w1) + b2 * bfhi(w2);
    ((float2*)out)[i] = r;
}

extern "C" void kernel_launch(void* const* d_in, const int* in_sizes, int n_in,
                              void* d_out, int out_size, void* d_ws, size_t ws_size,
                              hipStream_t stream) {
    const float* h        = (const float*)d_in[0];
    const int*   eidx     = (const int*)d_in[1];
    const float* W        = (const float*)d_in[2];
    const float* attn_l   = (const float*)d_in[3];
    const float* attn_r   = (const float*)d_in[4];
    const float* bias     = (const float*)d_in[5];
    const float* sem_W1   = (const float*)d_in[6];
    const float* sem_b1   = (const float*)d_in[7];
    const float* sem_W2   = (const float*)d_in[8];
    float* out = (float*)d_out;

    float* ws = (float*)d_ws;
    float* el   = ws;                                      // N*H
    float* er   = el + N_NODES * H_HEADS;                  // N*H
    float* wsum = er + N_NODES * H_HEADS;                  // 8
    float* beta = wsum + 8;                                // 8
    unsigned short* featb = (unsigned short*)(beta + 8);           // N*D bf16
    unsigned short* zb    = featb + (size_t)N_NODES * D_DIM;       // M*N*D bf16
    unsigned short* Wt    = zb + (size_t)M_PATHS * N_NODES * D_DIM;
    unsigned short* W1t   = Wt + (size_t)M_PATHS * D_DIM * IN_F;
    long long* pairs = (long long*)(W1t + (size_t)HID_DIM * D_DIM);  // 8*CAP pairs
    int* pcur    = (int*)(pairs + (size_t)8 * CAP);        // 8
    int* bsrc3   = pcur + 8;                               // M*E
    int* rowptr3 = bsrc3 + (size_t)M_PATHS * E_EDGES;      // M*(N+1)
    int* cursor3 = rowptr3 + M_PATHS * (N_NODES + 1);      // M*(N+1)
    int* deg3    = cursor3 + M_PATHS * (N_NODES + 1);      // M*N
    int* psum    = deg3 + M_PATHS * N_NODES;               // M*SCAN_NB

    hipMemsetAsync(wsum, 0, 16 * sizeof(float), stream);
    hipMemsetAsync(deg3, 0, M_PATHS * N_NODES * sizeof(int), stream);
    hipMemsetAsync(pcur, 0, 8 * sizeof(int), stream);

    // one-time weight prep
    transpose_w<<<dim3((IN_F * D_DIM + 255) / 256, M_PATHS), 256, 0, stream>>>(
        W, Wt, IN_F, D_DIM);
    transpose_w<<<dim3((D_DIM * HID_DIM + 255) / 256, 1), 256, 0, stream>>>(
        sem_W1, W1t, D_DIM, HID_DIM);

    // CSR build: partition -> count -> scan -> fill
    partition_edges<<<dim3(NCHUNK, M_PATHS), 256, 0, stream>>>(eidx, pcur, pairs);
    count_pairs<<<2048, 256, 0, stream>>>(pairs, pcur, deg3);
    scan_partial<<<dim3(SCAN_NB, M_PATHS), 256, 0, stream>>>(deg3, psum);
    scan_offsets<<<M_PATHS, 256, 0, stream>>>(psum, rowptr3);
    scan_final<<<dim3(SCAN_NB, M_PATHS), 256, 0, stream>>>(deg3, psum, rowptr3, cursor3);
    fill_pairs<<<2048, 256, 0, stream>>>(pairs, pcur, cursor3, bsrc3);

    for (int m = 0; m < M_PATHS; ++m) {
        const float* hm = h + (size_t)m * N_NODES * IN_F;
        unsigned short* zbm = zb + (size_t)m * N_NODES * D_DIM;

        gemm_feat_mfma<<<(N_NODES + 63) / 64, 256, 0, stream>>>(
            hm, Wt + (size_t)m * D_DIM * IN_F, featb);

        attn_dots<<<(N_NODES * H_HEADS + 255) / 256, 256, 0, stream>>>(
            (const unsigned*)featb, attn_l + m * H_HEADS * O_DIM,
            attn_r + m * H_HEADS * O_DIM, el, er);

        gather_z<<<N_NODES / 4, 256, 0, stream>>>(
            rowptr3 + m * (N_NODES + 1), bsrc3 + (size_t)m * E_EDGES, el, er,
            (const uint2*)featb, bias + m * D_DIM, (uint2*)zbm);

        semantic_mfma<<<(N_NODES + 63) / 64, 256, 0, stream>>>(
            zbm, W1t, sem_b1, sem_W2, wsum, m);
    }

    compute_beta<<<1, 1, 0, stream>>>(wsum, beta);
    final_mix<<<(N_NODES * (D_DIM / 2) + 255) / 256, 256, 0, stream>>>(
        (const unsigned*)zb, beta, out);
}